// Round 3
// baseline (242.245 us; speedup 1.0000x reference)
//
#include <hip/hip_runtime.h>
#include <math.h>

#define S_LEN 262144
#define N 128
#define TPB 256
#define GRID 768
#define NWAVES (GRID * 4)          // 3072 waves; 768 blocks == exactly resident at 3/CU
#define ITEMS (S_LEN / 16 * 2)     // strip(16 rows) x col-half = 32768 items

// two DISTINCT dwords: no repeated-pattern poison fill can forge this
#define FLAG_MAGIC 0x9E3779B185EBCA87ULL

typedef __attribute__((ext_vector_type(8))) short bf16x8;
typedef __attribute__((ext_vector_type(4))) float f32x4;

__device__ __forceinline__ unsigned short f2bf(float x) {
    unsigned b = __float_as_uint(x);
    b = (b + 0x7FFF + ((b >> 16) & 1)) >> 16;   // RNE to bf16
    return (unsigned short)b;
}
__device__ __forceinline__ float bf2f(unsigned short u) {
    return __uint_as_float((unsigned)u << 16);
}
// low16 = bf16(x), high16 = bf16(y) (round-half-up): 2 adds + 1 perm
__device__ __forceinline__ unsigned pack2bf(float x, float y) {
    return __builtin_amdgcn_perm(__float_as_uint(y) + 0x8000u,
                                 __float_as_uint(x) + 0x8000u, 0x07060302u);
}
__device__ __forceinline__ float wave_reduce(float v) {
    #pragma unroll
    for (int off = 32; off > 0; off >>= 1) v += __shfl_down(v, off, 64);
    return v;
}
// intra-wave LDS ordering fence: drain DS queue + stop compiler reordering.
// Does NOT touch vmcnt (global loads stay in flight) and is NOT a barrier.
__device__ __forceinline__ void lds_fence() {
    asm volatile("s_waitcnt lgkmcnt(0)" ::: "memory");
}

// Fused single kernel.
// Prologue: every wave issues its first Input strip loads (BW saturated from t=0).
// Blocks 0..7 then compute M = W_K^T @ W_Q (16 rows each, ~1us, hidden under the
// first-load latency flood), write bf16 MFMA-B fragments to ws fragB, and publish
// via agent-scope release flags. Block 7 waits flags 0..6, finalizes l1 -> out[1],
// zeroes out[0], releases flag 7. All waves acquire-spin on flag 7 before touching
// fragB / out[0] -- release/acquire chain makes the zero happen-before every
// atomicAdd with NO timing assumptions. Grid==capacity (768 @ 3/CU) => all blocks
// co-resident => flag writers always running => no deadlock.
__global__ __launch_bounds__(TPB, 3) void fused_kernel(
    const float* __restrict__ In, const float* __restrict__ WQ,
    const float* __restrict__ WK, unsigned short* __restrict__ fragB,
    float* __restrict__ wsP, unsigned long long* __restrict__ flags,
    float* __restrict__ out, float inv_denom) {
    __shared__ unsigned short sA[4][17][132];   // per-wave strip: 16 rows + boundary row
    __shared__ float sRed[4];

    const int tid = threadIdx.x;
    const int w = tid >> 6, lane = tid & 63;
    const int q = lane >> 4, n15 = lane & 15;
    const int gid = blockIdx.x * 4 + w;          // global wave id
    const int half = gid & 1;                    // col half (item stride is even)

    unsigned short (*my)[132] = sA[w];
    float lsum = 0.f;
    float4 r[8];
    float2 x;

    auto issue = [&](int item) {
        const long r0 = (long)(item >> 1) * 16;
        const float* base = In + r0 * N;
        #pragma unroll
        for (int j = 0; j < 8; ++j)              // 8 x 1KB chunks: rows 2j, 2j+1
            r[j] = *(const float4*)(base + j * 256 + lane * 4);
        long rX = r0 + 16; if (rX > S_LEN - 1) rX = S_LEN - 1;
        x = *(const float2*)&In[rX * N + lane * 2];   // boundary row, all 64 lanes
    };

    // first item's HBM loads in flight BEFORE anything else
    int item = gid;
    issue(item);

    // ---- M-compute prologue (blocks 0..7 only) ----
    if (blockIdx.x < 8) {
        const int g = blockIdx.x;
        const int mr = g * 16 + (tid >> 4);      // M row (= k index of main GEMM)
        const int c0 = (tid & 15) * 8;           // first of 8 M cols for this thread
        float a[8];
        #pragma unroll
        for (int e = 0; e < 8; ++e) a[e] = 0.f;
        #pragma unroll 16
        for (int r2 = 0; r2 < N; ++r2) {
            const float wk = WK[r2 * N + mr];
            const float4 q0 = *(const float4*)&WQ[r2 * N + c0];
            const float4 q1 = *(const float4*)&WQ[r2 * N + c0 + 4];
            a[0] = fmaf(wk, q0.x, a[0]); a[1] = fmaf(wk, q0.y, a[1]);
            a[2] = fmaf(wk, q0.z, a[2]); a[3] = fmaf(wk, q0.w, a[3]);
            a[4] = fmaf(wk, q1.x, a[4]); a[5] = fmaf(wk, q1.y, a[5]);
            a[6] = fmaf(wk, q1.z, a[6]); a[7] = fmaf(wk, q1.w, a[7]);
        }
        const int kk = mr >> 5, q8 = (mr >> 3) & 3, jj = mr & 7;
        float sg = 0.f;
        #pragma unroll
        for (int cc = 0; cc < 8; ++cc) {
            const int c = c0 + cc;
            fragB[((kk * 8 + (c >> 4)) * 64 + (q8 * 16 + (c & 15))) * 8 + jj] = f2bf(a[cc]);
            sg += fabsf(1.0f / (1.0f + __expf(-a[cc])));
        }
        float wsum = wave_reduce(sg);
        if ((tid & 63) == 0) sRed[tid >> 6] = wsum;
        __syncthreads();
        if (tid == 0) {
            const float p = sRed[0] + sRed[1] + sRed[2] + sRed[3];
            if (g < 7) {
                wsP[g] = p;
                __hip_atomic_store(&flags[g], FLAG_MAGIC, __ATOMIC_RELEASE,
                                   __HIP_MEMORY_SCOPE_AGENT);
            } else {
                #pragma unroll 1
                for (int gg = 0; gg < 7; ++gg)
                    while (__hip_atomic_load(&flags[gg], __ATOMIC_RELAXED,
                                             __HIP_MEMORY_SCOPE_AGENT) != FLAG_MAGIC)
                        __builtin_amdgcn_s_sleep(1);
                __builtin_amdgcn_fence(__ATOMIC_ACQUIRE, "agent");
                float t = 0.f;
                #pragma unroll 1
                for (int gg = 0; gg < 7; ++gg) t += wsP[gg];
                t += p;
                out[1] = t;
                out[0] = 0.f;                    // published by flag 7 release below
                __hip_atomic_store(&flags[7], FLAG_MAGIC, __ATOMIC_RELEASE,
                                   __HIP_MEMORY_SCOPE_AGENT);
            }
        }
    }

    // ---- acquire fragB + zeroed out[0] (wait hides under first-load latency) ----
    while (__hip_atomic_load(&flags[7], __ATOMIC_RELAXED,
                             __HIP_MEMORY_SCOPE_AGENT) != FLAG_MAGIC)
        __builtin_amdgcn_s_sleep(8);
    __builtin_amdgcn_fence(__ATOMIC_ACQUIRE, "agent");

    // B fragments for this wave's 64 cols (ct = half*4 + c4), constant all kernel
    bf16x8 bF[4][4];
    #pragma unroll
    for (int c4 = 0; c4 < 4; ++c4)
        #pragma unroll
        for (int kk = 0; kk < 4; ++kk)
            bF[c4][kk] = *(const bf16x8*)&fragB[((kk * 8 + (half * 4 + c4)) * 64 + lane) * 8];

    bf16x8 bOne;   // all-ones B: rowsum via MFMA, C/D layout matches epilogue
    #pragma unroll
    for (int e = 0; e < 8; ++e) bOne[e] = (short)0x3F80;

    while (item < ITEMS) {
        const int next = item + NWAVES;

        // pack fp32 regs -> bf16 LDS strip (compiler inserts vmcnt waits for r/x)
        #pragma unroll
        for (int j = 0; j < 8; ++j) {
            const int row = 2 * j + (lane >> 5);
            const int c = lane & 31;
            *(unsigned int*)&my[row][c * 4] = pack2bf(r[j].x, r[j].y);
            *(unsigned int*)&my[row][c * 4 + 2] = pack2bf(r[j].z, r[j].w);
        }
        *(unsigned int*)&my[16][lane * 2] = pack2bf(x.x, x.y);

        // immediately put next item's loads in flight (r, x now dead)
        if (next < ITEMS) issue(next);

        lds_fence();   // pack visible to all lanes of this wave before fragment reads

        // MFMA: z (4 col-tiles) + rowsum, K=128
        f32x4 acc[4], aRS;
        aRS = (f32x4){0.f, 0.f, 0.f, 0.f};
        #pragma unroll
        for (int c4 = 0; c4 < 4; ++c4) acc[c4] = (f32x4){0.f, 0.f, 0.f, 0.f};
        #pragma unroll
        for (int kk = 0; kk < 4; ++kk) {
            bf16x8 a = *(const bf16x8*)&my[n15][kk * 32 + q * 8];  // A[m=n15][k=q*8+j]
            aRS = __builtin_amdgcn_mfma_f32_16x16x32_bf16(a, bOne, aRS, 0, 0, 0);
            #pragma unroll
            for (int c4 = 0; c4 < 4; ++c4)
                acc[c4] = __builtin_amdgcn_mfma_f32_16x16x32_bf16(a, bF[c4][kk], acc[c4], 0, 0, 0);
        }

        // epilogue: C/D row = q*4+reg, col = n15 (per 16-tile)
        const long r0 = (long)(item >> 1) * 16;
        #pragma unroll
        for (int reg = 0; reg < 4; ++reg) {
            const int row = q * 4 + reg;
            const float rs = aRS[reg];
            const long s = r0 + row;
            const bool has = (s < S_LEN - 1);
            #pragma unroll
            for (int c4 = 0; c4 < 4; ++c4) {
                const float z = acc[c4][reg];
                const float sp = fmaxf(z, 0.f) + __logf(1.0f + __expf(-fabsf(z)));
                const float o = sp * rs;
                if (has) {
                    const int col = half * 64 + c4 * 16 + n15;
                    const float d = o - bf2f(my[row + 1][col]);
                    lsum = fmaf(d, d, lsum);
                }
            }
        }

        lds_fence();   // epilogue LDS reads done before next iteration's pack overwrites
        item = next;
    }

    const float wsum = wave_reduce(lsum);
    if ((tid & 63) == 0) sRed[w] = wsum;
    __syncthreads();
    if (tid == 0) {
        float t = 0.f;
        #pragma unroll
        for (int w2 = 0; w2 < 4; ++w2) t += sRed[w2];
        atomicAdd(&out[0], t * inv_denom);   // out[0]=0 happens-before via flag-7 acq
    }
}

extern "C" void kernel_launch(void* const* d_in, const int* in_sizes, int n_in,
                              void* d_out, int out_size, void* d_ws, size_t ws_size,
                              hipStream_t stream) {
    const float* In = (const float*)d_in[0];
    const float* WQ = (const float*)d_in[1];
    const float* WK = (const float*)d_in[2];
    float* out = (float*)d_out;
    unsigned short* fragB = (unsigned short*)d_ws;                       // 32 KB
    float* wsP = (float*)((char*)d_ws + 32768);                          // 8 floats
    unsigned long long* flags = (unsigned long long*)((char*)d_ws + 32832); // 8 x u64

    const float inv = (float)(1.0 / ((double)(S_LEN - 1) * (double)N));
    fused_kernel<<<GRID, TPB, 0, stream>>>(In, WQ, WK, fragB, wsP, flags, out, inv);
}

// Round 4
// 202.660 us; speedup vs baseline: 1.1953x; 1.1953x over previous
//
#include <hip/hip_runtime.h>
#include <math.h>

#define S_LEN 262144
#define N 128
#define TPB 256
#define GRID 768
#define NWAVES (GRID * 4)          // 3072 waves
#define ITEMS (S_LEN / 16 * 2)     // strip(16 rows) x col-half = 32768 items

typedef __attribute__((ext_vector_type(8))) short bf16x8;
typedef __attribute__((ext_vector_type(4))) float f32x4;

__device__ __forceinline__ unsigned short f2bf(float x) {
    unsigned b = __float_as_uint(x);
    b = (b + 0x7FFF + ((b >> 16) & 1)) >> 16;   // RNE to bf16
    return (unsigned short)b;
}
__device__ __forceinline__ float bf2f(unsigned short u) {
    return __uint_as_float((unsigned)u << 16);
}
// low16 = bf16(x), high16 = bf16(y) (round-half-up): 2 adds + 1 perm
__device__ __forceinline__ unsigned pack2bf(float x, float y) {
    return __builtin_amdgcn_perm(__float_as_uint(y) + 0x8000u,
                                 __float_as_uint(x) + 0x8000u, 0x07060302u);
}
__device__ __forceinline__ float wave_reduce(float v) {
    #pragma unroll
    for (int off = 32; off > 0; off >>= 1) v += __shfl_down(v, off, 64);
    return v;
}
// intra-wave LDS ordering fence: drain DS queue + stop compiler reordering.
// Does NOT touch vmcnt (global loads stay in flight) and is NOT a barrier.
__device__ __forceinline__ void lds_fence() {
    asm volatile("s_waitcnt lgkmcnt(0)" ::: "memory");
}

// M = W_K^T @ W_Q (128x128) fp32; emit bf16 in MFMA-B-fragment order:
//   frag[((kk*8 + ct)*64 + lane)*8 + j] = M[kk*32 + (lane>>4)*8 + j][ct*16 + (lane&15)]
// l1 partials (sum sigmoid(M) per block) -> wsP[block]; out[0] zeroed here so
// main_kernel's atomics land on a clean slate (kernel-boundary ordering).
// Full unroll + 4 accumulator chains keeps ~32 cold-HBM loads in flight.
__global__ void mk_kernel(const float* __restrict__ WQ, const float* __restrict__ WK,
                          unsigned short* __restrict__ fragB, float* __restrict__ wsP,
                          float* __restrict__ out) {
    const int i = blockIdx.x;   // M row (k of main GEMM) -- uniform => scalar loads
    const int j = threadIdx.x;  // M col
    float a0 = 0.f, a1 = 0.f, a2 = 0.f, a3 = 0.f;
    #pragma unroll
    for (int r = 0; r < N; r += 4) {
        a0 = fmaf(WK[(r + 0) * N + i], WQ[(r + 0) * N + j], a0);
        a1 = fmaf(WK[(r + 1) * N + i], WQ[(r + 1) * N + j], a1);
        a2 = fmaf(WK[(r + 2) * N + i], WQ[(r + 2) * N + j], a2);
        a3 = fmaf(WK[(r + 3) * N + i], WQ[(r + 3) * N + j], a3);
    }
    const float acc = (a0 + a1) + (a2 + a3);

    const int kk = i >> 5, q = (i >> 3) & 3, jj = i & 7;
    const int ct = j >> 4, n15 = j & 15;
    fragB[((kk * 8 + ct) * 64 + (q * 16 + n15)) * 8 + jj] = f2bf(acc);

    float sg = fabsf(1.0f / (1.0f + __expf(-acc)));
    float ws = wave_reduce(sg);
    __shared__ float red[2];
    if ((j & 63) == 0) red[j >> 6] = ws;
    __syncthreads();
    if (j == 0) wsP[i] = red[0] + red[1];
    if (i == 0 && j == 0) out[0] = 0.f;
}

// Wave-autonomous: each wave owns (strip of 16 rows) x (64 cols). The duplicate
// strip read by the paired col-half wave is an L2/L3 hit, so HBM fetch ~134 MB.
// Per-wave LDS strip is DOUBLE-BUFFERED: item i+1's pack writes buf^1 while
// item i's epilogue reads buf -- removes the tail lgkmcnt(0) drain and lets the
// compiler interleave pack stores with epilogue math. Only ordering point left
// per iteration is the pack->MFMA fence.
__global__ __launch_bounds__(TPB, 3) void main_kernel(
    const float* __restrict__ In, const unsigned short* __restrict__ fragB,
    const float* __restrict__ wsP, float* __restrict__ out, float inv_denom) {
    __shared__ unsigned short sA[4][2][17][132];  // per-wave strip x2: 16 rows + boundary
    __shared__ float sRed[4];

    const int tid = threadIdx.x;
    const int w = tid >> 6, lane = tid & 63;
    const int q = lane >> 4, n15 = lane & 15;
    const int gid = blockIdx.x * 4 + w;          // global wave id
    const int half = gid & 1;                    // col half (item stride is even)

    float lsum = 0.f;
    float4 r[8];
    float2 x;

    auto issue = [&](int item) {
        const long r0 = (long)(item >> 1) * 16;
        const float* base = In + r0 * N;
        #pragma unroll
        for (int j = 0; j < 8; ++j)              // 8 x 1KB chunks: rows 2j, 2j+1
            r[j] = *(const float4*)(base + j * 256 + lane * 4);
        long rX = r0 + 16; if (rX > S_LEN - 1) rX = S_LEN - 1;
        x = *(const float2*)&In[rX * N + lane * 2];   // boundary row, all 64 lanes
    };

    // put the first item's HBM loads in flight BEFORE touching fragB: the
    // fragment loads (L2-resident, mk just wrote them) hide under HBM latency
    int item = gid;
    issue(item);

    // B fragments for this wave's 64 cols (ct = half*4 + c4), constant all kernel
    bf16x8 bF[4][4];
    #pragma unroll
    for (int c4 = 0; c4 < 4; ++c4)
        #pragma unroll
        for (int kk = 0; kk < 4; ++kk)
            bF[c4][kk] = *(const bf16x8*)&fragB[((kk * 8 + (half * 4 + c4)) * 64 + lane) * 8];

    bf16x8 bOne;   // all-ones B: rowsum via MFMA, C/D layout matches epilogue
    #pragma unroll
    for (int e = 0; e < 8; ++e) bOne[e] = (short)0x3F80;

    // block 0, wave 0: finalize l1 from mk's 128 per-block partials (single writer)
    if (blockIdx.x == 0 && w == 0) {
        float p = wsP[lane] + wsP[lane + 64];
        float s = wave_reduce(p);
        if (lane == 0) out[1] = s;
    }

    int cur = 0;
    while (item < ITEMS) {
        const int next = item + NWAVES;
        unsigned short (*my)[132] = sA[w][cur];

        // pack fp32 regs -> bf16 LDS strip (compiler inserts vmcnt waits for r/x)
        #pragma unroll
        for (int j = 0; j < 8; ++j) {
            const int row = 2 * j + (lane >> 5);
            const int c = lane & 31;
            *(unsigned int*)&my[row][c * 4] = pack2bf(r[j].x, r[j].y);
            *(unsigned int*)&my[row][c * 4 + 2] = pack2bf(r[j].z, r[j].w);
        }
        *(unsigned int*)&my[16][lane * 2] = pack2bf(x.x, x.y);

        // immediately put next item's loads in flight (r, x now dead)
        if (next < ITEMS) issue(next);

        lds_fence();   // pack visible to all lanes of this wave before fragment reads

        // MFMA: z (4 col-tiles) + rowsum, K=128
        f32x4 acc[4], aRS;
        aRS = (f32x4){0.f, 0.f, 0.f, 0.f};
        #pragma unroll
        for (int c4 = 0; c4 < 4; ++c4) acc[c4] = (f32x4){0.f, 0.f, 0.f, 0.f};
        #pragma unroll
        for (int kk = 0; kk < 4; ++kk) {
            bf16x8 a = *(const bf16x8*)&my[n15][kk * 32 + q * 8];  // A[m=n15][k=q*8+j]
            aRS = __builtin_amdgcn_mfma_f32_16x16x32_bf16(a, bOne, aRS, 0, 0, 0);
            #pragma unroll
            for (int c4 = 0; c4 < 4; ++c4)
                acc[c4] = __builtin_amdgcn_mfma_f32_16x16x32_bf16(a, bF[c4][kk], acc[c4], 0, 0, 0);
        }

        // epilogue: C/D row = q*4+reg, col = n15 (per 16-tile); reads CURRENT buf,
        // next iteration packs into the OTHER buf -- no tail fence needed.
        const long r0 = (long)(item >> 1) * 16;
        #pragma unroll
        for (int reg = 0; reg < 4; ++reg) {
            const int row = q * 4 + reg;
            const float rs = aRS[reg];
            const long s = r0 + row;
            const bool has = (s < S_LEN - 1);
            #pragma unroll
            for (int c4 = 0; c4 < 4; ++c4) {
                const float z = acc[c4][reg];
                const float sp = fmaxf(z, 0.f) + __logf(1.0f + __expf(-fabsf(z)));
                const float o = sp * rs;
                if (has) {
                    const int col = half * 64 + c4 * 16 + n15;
                    const float d = o - bf2f(my[row + 1][col]);
                    lsum = fmaf(d, d, lsum);
                }
            }
        }

        cur ^= 1;
        item = next;
    }

    const float wsum = wave_reduce(lsum);
    if ((tid & 63) == 0) sRed[w] = wsum;
    __syncthreads();
    if (tid == 0) {
        float t = 0.f;
        #pragma unroll
        for (int w2 = 0; w2 < 4; ++w2) t += sRed[w2];
        atomicAdd(&out[0], t * inv_denom);
    }
}

extern "C" void kernel_launch(void* const* d_in, const int* in_sizes, int n_in,
                              void* d_out, int out_size, void* d_ws, size_t ws_size,
                              hipStream_t stream) {
    const float* In = (const float*)d_in[0];
    const float* WQ = (const float*)d_in[1];
    const float* WK = (const float*)d_in[2];
    float* out = (float*)d_out;
    unsigned short* fragB = (unsigned short*)d_ws;          // 32 KB
    float* wsP = (float*)((char*)d_ws + 32 * 1024);         // 128 floats: l1 partials

    mk_kernel<<<128, 128, 0, stream>>>(WQ, WK, fragB, wsP, out);
    const float inv = (float)(1.0 / ((double)(S_LEN - 1) * (double)N));
    main_kernel<<<GRID, TPB, 0, stream>>>(In, fragB, wsP, out, inv);
}